// Round 6
// baseline (376.790 us; speedup 1.0000x reference)
//
#include <hip/hip_runtime.h>

// Weighted BP decoder, (3,6)-regular Tanner graph.
// Check r owns edges 6r..6r+5 (row-major nonzeros of H) -> check-side extrinsic
// products are in-register prefix/suffix products (c_prod_idx unused).
//
// Messages in log2 domain: d = c2v/ln2. With z = exp2(a), t = tanh(a*ln2/2)
// = (z-1)/(z+1); extrinsic product p = A/B with A = prod(z-1), B = prod(z+1)
// (all-but-one). Then
//   d_new = log2(B + kappa*A) - log2(B - kappa*A)
// -> per edge-row transcendentals: exp2 + 2*log2 (tanh/atanh never formed).
// Exponent clamped at 24 (== z <= 2^24): 5-way products <= 2^120, and
// B >= |A| keeps both log args >= (1-kappa)*B > 0.
//
// R11 = R9 (146 us, best verified) + two micro-levers; R10's persistence is
// reverted (group loop pushed peak pressure past the 64-VGPR cap -> scratch
// spill: FETCH 18.8->402 MB, 266 us).
//  - Iter-0 elision WITHOUT persistence: messages are zero at iter 0, so
//    the 49KB zero-init, its barrier, and iter-0's 12 zero-gathers+fmas are
//    skipped; a[j] = Lpre[j]*lv[j] exactly (bit-identical: fma(w,0,x)==x).
//    Iter-0's writes cover all 3072 slots (swizzle is a bijection), so no
//    init is needed. 19 barriers instead of 21. Single-group -> live set
//    identical to R9 -> no spill path.
//  - s_setprio(1) around the transcendental tail: the two co-resident
//    blocks are NOT barrier-synced to each other -> real phase diversity
//    (one block gathers/waits while the other runs its trans tail), the
//    regime where setprio measured +4-7% (attn m191), not the lockstep
//    regime where it was null. Hint only; correctness unaffected.
//
// Occupancy model (calibrated R5-R10): VGPR file = 256/lane/SIMD;
// __launch_bounds__(T,n) -> VGPR cap 256/n; waves/SIMD = floor(256/VGPR).
// ROWS=4 @ 64 VGPR -> 4 waves/SIMD, 16 rows in flight = session optimum.
// More waves needs <=42 VGPR (unreachable); fewer barriers via dbuf loses
// TLP (R8); persistence spills (R10). Conflicts solved by swz (9.2e5 res.).

namespace {

typedef float v4f __attribute__((ext_vector_type(4)));

constexpr int T      = 512;   // threads/block == checks
constexpr int ROWS   = 4;     // batch rows per block (v4f-packed)
constexpr int EEDG   = 3072;
constexpr int NVAR   = 1024;
constexpr int NITER  = 10;
constexpr int BATCH  = 8192;
constexpr int NOUT   = 512;   // N - M outputs per row

constexpr float LOG2E = 1.4426950408889634f;
constexpr float LN2   = 0.6931471805599453f;
constexpr float KAPPA = 0.999995f;
constexpr float ACLMP = 24.0f;   // exp2 arg clamp == z <= 2^24

__device__ __forceinline__ float fast_exp2(float x) { return __builtin_amdgcn_exp2f(x); }
__device__ __forceinline__ float fast_log2(float x) { return __builtin_amdgcn_logf(x); }
__device__ __forceinline__ float fast_rcp (float x) { return __builtin_amdgcn_rcpf(x); }

// Bank-conflict swizzle: rotate low 5 bits of the slot right by 1 (bijective
// within every 32-slot chunk; 3072 = 96*32). 16B slots: bank-quad group =
// (s>>1)&7; stride-6 slot progressions -> group stride 3 (odd) ->
// conflict-free b128 gathers AND own-slot writes (validated R8/R9:
// conflicts 1.62e7 -> 9.2e5).
__device__ __forceinline__ int swz(int s) {
    return (s & ~31) | ((s >> 1) & 15) | ((s & 1) << 4);
}

__global__ __launch_bounds__(T, 4)   // min 4 waves/EU -> VGPR cap 256/4 = 64
void bp_decode(const float* __restrict__ llr,
               const float* __restrict__ w_iter,
               const float* __restrict__ llr_iter,
               const float* __restrict__ w_final,
               const float* __restrict__ llr_final,
               const int*  __restrict__ v_sum_idx,
               const int*  __restrict__ edge_var,
               const int*  __restrict__ final_idx,
               float* __restrict__ out)
{
    __shared__ v4f Ad[EEDG];   // 49152 B; 2 blocks/CU co-resident

    const int  tid = threadIdx.x;
    const long b0  = (long)blockIdx.x * ROWS;
    const int  own = 6 * tid;

    // ---- static per-thread graph data (my check = tid, edges 6*tid..6*tid+5) ----
    unsigned nbp[6];    // my 12 neighbor LDS slots (swizzled), 2x16b packed
    unsigned varp[3];   // my 6 variable ids, 2x16b packed
    v4f      Lpre[6];   // llr (4 rows) * LOG2E per edge
    {
        const int4* p = (const int4*)(v_sum_idx + 12 * tid);  // 48B-aligned
        int4 q0 = p[0], q1 = p[1], q2 = p[2];
        nbp[0] = (unsigned)swz(q0.x) | ((unsigned)swz(q0.y) << 16);
        nbp[1] = (unsigned)swz(q0.z) | ((unsigned)swz(q0.w) << 16);
        nbp[2] = (unsigned)swz(q1.x) | ((unsigned)swz(q1.y) << 16);
        nbp[3] = (unsigned)swz(q1.z) | ((unsigned)swz(q1.w) << 16);
        nbp[4] = (unsigned)swz(q2.x) | ((unsigned)swz(q2.y) << 16);
        nbp[5] = (unsigned)swz(q2.z) | ((unsigned)swz(q2.w) << 16);
    }
    {
        int var[6];
        const int2* p = (const int2*)(edge_var + 6 * tid);    // 24B-aligned
        int2 q0 = p[0], q1 = p[1], q2 = p[2];
        var[0]=q0.x; var[1]=q0.y; var[2]=q1.x; var[3]=q1.y; var[4]=q2.x; var[5]=q2.y;
        #pragma unroll
        for (int i = 0; i < 3; ++i)
            varp[i] = (unsigned)var[2*i] | ((unsigned)var[2*i+1] << 16);
        #pragma unroll
        for (int j = 0; j < 6; ++j) {
            v4f L;
            L.x = llr[(b0 + 0) * NVAR + var[j]];
            L.y = llr[(b0 + 1) * NVAR + var[j]];
            L.z = llr[(b0 + 2) * NVAR + var[j]];
            L.w = llr[(b0 + 3) * NVAR + var[j]];
            Lpre[j] = L * LOG2E;
        }
    }

    // prefetch iteration 0 uniforms
    float w[12], lv[6];
    {
        const float* p = w_iter + 12 * tid;
        float4 a4 = ((const float4*)p)[0], b4 = ((const float4*)p)[1], c4 = ((const float4*)p)[2];
        w[0]=a4.x; w[1]=a4.y; w[2]=a4.z;  w[3]=a4.w;
        w[4]=b4.x; w[5]=b4.y; w[6]=b4.z;  w[7]=b4.w;
        w[8]=c4.x; w[9]=c4.y; w[10]=c4.z; w[11]=c4.w;
        #pragma unroll
        for (int i = 0; i < 3; ++i) {
            unsigned q = varp[i];
            lv[2*i]   = llr_iter[q & 0xffffu];
            lv[2*i+1] = llr_iter[q >> 16];
        }
    }

    // Post-gather region of one iteration: prefetch uniforms for ITN,
    // z-domain check update from a[], write messages, rotate uniforms.
    // setprio(1) around the trans-heavy core: the co-resident block is at an
    // independent phase; favor the wave that is feeding the trans pipe.
#define BP_TAIL(ITN) do {                                                       \
        const int itn_ = (ITN);                                                 \
        const float* pw_ = w_iter + (long)itn_ * (EEDG * 2) + 12 * tid;         \
        float4 qa_ = ((const float4*)pw_)[0];                                   \
        float4 qb_ = ((const float4*)pw_)[1];                                   \
        float4 qc_ = ((const float4*)pw_)[2];                                   \
        const float* lit_ = llr_iter + itn_ * NVAR;                             \
        float lvn_[6];                                                          \
        _Pragma("unroll")                                                       \
        for (int i = 0; i < 3; ++i) {                                           \
            unsigned q = varp[i];                                               \
            lvn_[2*i]   = lit_[q & 0xffffu];                                    \
            lvn_[2*i+1] = lit_[q >> 16];                                        \
        }                                                                       \
        __builtin_amdgcn_s_setprio(1);                                          \
        v4f zm_[6], zp_[6];                                                     \
        _Pragma("unroll")                                                       \
        for (int j = 0; j < 6; ++j) {                                           \
            v4f aa = __builtin_elementwise_min(a[j], (v4f)(ACLMP));             \
            v4f z;                                                              \
            z.x = fast_exp2(aa.x);                                              \
            z.y = fast_exp2(aa.y);                                              \
            z.z = fast_exp2(aa.z);                                              \
            z.w = fast_exp2(aa.w);                                              \
            zm_[j] = z - 1.f;                                                   \
            zp_[j] = z + 1.f;                                                   \
        }                                                                       \
        v4f A_[6], B_[6];                                                       \
        {                                                                       \
            v4f P1=zm_[0], P2=P1*zm_[1], P3=P2*zm_[2], P4=P3*zm_[3], P5=P4*zm_[4]; \
            v4f S4=zm_[5], S3=S4*zm_[4], S2=S3*zm_[3], S1=S2*zm_[2], S0=S1*zm_[1]; \
            A_[0]=S0; A_[1]=P1*S1; A_[2]=P2*S2; A_[3]=P3*S3; A_[4]=P4*S4; A_[5]=P5; \
        }                                                                       \
        {                                                                       \
            v4f P1=zp_[0], P2=P1*zp_[1], P3=P2*zp_[2], P4=P3*zp_[3], P5=P4*zp_[4]; \
            v4f S4=zp_[5], S3=S4*zp_[4], S2=S3*zp_[3], S1=S2*zp_[2], S0=S1*zp_[1]; \
            B_[0]=S0; B_[1]=P1*S1; B_[2]=P2*S2; B_[3]=P3*S3; B_[4]=P4*S4; B_[5]=P5; \
        }                                                                       \
        _Pragma("unroll")                                                       \
        for (int j = 0; j < 6; ++j) {                                           \
            v4f num = KAPPA * A_[j] + B_[j];    /* pk fma */                    \
            v4f den = B_[j] - KAPPA * A_[j];    /* pk fma */                    \
            v4f d;                                                              \
            d.x = fast_log2(num.x) - fast_log2(den.x);                          \
            d.y = fast_log2(num.y) - fast_log2(den.y);                          \
            d.z = fast_log2(num.z) - fast_log2(den.z);                          \
            d.w = fast_log2(num.w) - fast_log2(den.w);                          \
            Ad[swz(own + j)] = d;               /* ds_write_b128, conflict-free */ \
        }                                                                       \
        __builtin_amdgcn_s_setprio(0);                                          \
        w[0]=qa_.x; w[1]=qa_.y; w[2]=qa_.z;  w[3]=qa_.w;                        \
        w[4]=qb_.x; w[5]=qb_.y; w[6]=qb_.z;  w[7]=qb_.w;                        \
        w[8]=qc_.x; w[9]=qc_.y; w[10]=qc_.z; w[11]=qc_.w;                       \
        _Pragma("unroll")                                                       \
        for (int j = 0; j < 6; ++j) lv[j] = lvn_[j];                            \
    } while (0)

    // ---- iteration 0: messages are all zero -> zero-init, init barrier,
    // and gathers elided exactly (fma(w,0,x)==x). Iter-0 writes cover all
    // 3072 slots (swizzle is a bijection); no thread reads LDS before. ----
    {
        v4f a[6];
        #pragma unroll
        for (int j = 0; j < 6; ++j) a[j] = Lpre[j] * lv[j];
        BP_TAIL(1);
        __syncthreads();   // iter-0 writes visible before iter-1 gathers
    }

    // ---- iterations 1..9 ----
    #pragma unroll 3
    for (int it = 1; it < NITER; ++it) {
        // accumulators seeded with channel term; LDS gathers folded in
        v4f a[6];
        #pragma unroll
        for (int j = 0; j < 6; ++j) a[j] = Lpre[j] * lv[j];
        #pragma unroll
        for (int i = 0; i < 6; ++i) {
            unsigned p  = nbp[i];
            v4f ga = Ad[p & 0xffffu];     // ds_read_b128, conflict-free
            v4f gb = Ad[p >> 16];
            a[i] = a[i] + w[2*i] * ga + w[2*i+1] * gb;   // pk fma
        }

        __syncthreads();   // all gathers landed before anyone overwrites in place
        BP_TAIL((it + 1 < NITER) ? it + 1 : it);   // clamp, no OOB
        __syncthreads();   // writes visible before next iteration's gathers
    }
#undef BP_TAIL

    // ---- final marginalization: variable tid (the 512 output vars), 4 rows ----
    {
        int f0 = swz(final_idx[3*tid]), f1 = swz(final_idx[3*tid + 1]), f2 = swz(final_idx[3*tid + 2]);
        v4f d0 = Ad[f0];
        v4f d1 = Ad[f1];
        v4f d2 = Ad[f2];
        float wf0 = w_final[3*tid], wf1 = w_final[3*tid + 1], wf2 = w_final[3*tid + 2];
        float lf  = llr_final[tid];
        v4f l;
        l.x = llr[(b0 + 0) * NVAR + tid];
        l.y = llr[(b0 + 1) * NVAR + tid];
        l.z = llr[(b0 + 2) * NVAR + tid];
        l.w = llr[(b0 + 3) * NVAR + tid];

        v4f fin = (d0 * wf0 + d1 * wf1 + d2 * wf2) * LN2;   // c2v = ln2 * d
        v4f v   = l * lf + fin;
        out[(b0 + 0) * NOUT + tid] = fast_rcp(1.f + fast_exp2(-v.x * LOG2E));
        out[(b0 + 1) * NOUT + tid] = fast_rcp(1.f + fast_exp2(-v.y * LOG2E));
        out[(b0 + 2) * NOUT + tid] = fast_rcp(1.f + fast_exp2(-v.z * LOG2E));
        out[(b0 + 3) * NOUT + tid] = fast_rcp(1.f + fast_exp2(-v.w * LOG2E));
    }
}

} // namespace

extern "C" void kernel_launch(void* const* d_in, const int* in_sizes, int n_in,
                              void* d_out, int out_size, void* d_ws, size_t ws_size,
                              hipStream_t stream)
{
    const float* llr       = (const float*)d_in[0];
    const float* w_iter    = (const float*)d_in[1];
    const float* llr_iter  = (const float*)d_in[2];
    const float* w_final   = (const float*)d_in[3];
    const float* llr_final = (const float*)d_in[4];
    const int*   v_sum_idx = (const int*)d_in[5];
    // d_in[6] = c_prod_idx: unused (check groups are consecutive by construction)
    const int*   edge_var  = (const int*)d_in[7];
    const int*   final_idx = (const int*)d_in[8];
    float* outp = (float*)d_out;

    dim3 grid(BATCH / ROWS), block(T);
    hipLaunchKernelGGL(bp_decode, grid, block, 0, stream,
                       llr, w_iter, llr_iter, w_final, llr_final,
                       v_sum_idx, edge_var, final_idx, outp);
}

// Round 7
// 226.326 us; speedup vs baseline: 1.6648x; 1.6648x over previous
//
#include <hip/hip_runtime.h>

// Weighted BP decoder, (3,6)-regular Tanner graph.
// Check r owns edges 6r..6r+5 (row-major nonzeros of H) -> check-side extrinsic
// products are in-register prefix/suffix products (c_prod_idx unused).
//
// Messages in log2 domain: d = c2v/ln2. With z = exp2(a), t = tanh(a*ln2/2)
// = (z-1)/(z+1); extrinsic product p = A/B with A = prod(z-1), B = prod(z+1)
// (all-but-one). Then
//   d_new = log2(B + kappa*A) - log2(B - kappa*A)
// -> per edge-row transcendentals: exp2 + 2*log2 (tanh/atanh never formed).
// Exponent clamped at 24 (== z <= 2^24): 5-way products <= 2^120, and
// B >= |A| keeps both log args >= (1-kappa)*B > 0.
//
// R12 = R9 (146 us, best verified) + MINIMAL-DIFF iter-0 elision.
//  - R10/R11 post-mortem: R9's allocation sits exactly at the 64-VGPR cap;
//    any nontrivial scheduling perturbation (group loop, tail duplication,
//    setprio fences, unroll change) tips it into scratch spill (FETCH
//    18.8 -> 400+ MB). Admissible edits are minimal diffs only, validated
//    by FETCH_SIZE staying ~18 MB.
//  - This round's single change: messages are all zero at iteration 0, so
//    the 49KB zero-init and iter-0's 12 LDS gathers + 24 pk-fmas are dead
//    work. Elide via a runtime uniform branch `if (it)` around the gather
//    loop (2 SALU/iter) -- NO tail duplication, NO unroll change, NO
//    setprio. Bit-identical: fma(w,0,x)==x, and iter-0's writes cover all
//    3072 slots (swizzle is a bijection) before any LDS read.
//
// Occupancy model (calibrated R5-R11): VGPR file = 256/lane/SIMD;
// __launch_bounds__(T,n) -> VGPR cap 256/n; waves/SIMD = floor(256/VGPR).
// ROWS=4 @ 64 VGPR -> 4 waves/SIMD, 16 rows in flight = session optimum.
// More waves needs <=42 VGPR (unreachable); dbuf loses TLP (R8);
// persistence spills (R10); conflicts solved by swz (9.2e5 residual).

namespace {

typedef float v4f __attribute__((ext_vector_type(4)));

constexpr int T      = 512;   // threads/block == checks
constexpr int ROWS   = 4;     // batch rows per block (v4f-packed)
constexpr int EEDG   = 3072;
constexpr int NVAR   = 1024;
constexpr int NITER  = 10;
constexpr int BATCH  = 8192;
constexpr int NOUT   = 512;   // N - M outputs per row

constexpr float LOG2E = 1.4426950408889634f;
constexpr float LN2   = 0.6931471805599453f;
constexpr float KAPPA = 0.999995f;
constexpr float ACLMP = 24.0f;   // exp2 arg clamp == z <= 2^24

__device__ __forceinline__ float fast_exp2(float x) { return __builtin_amdgcn_exp2f(x); }
__device__ __forceinline__ float fast_log2(float x) { return __builtin_amdgcn_logf(x); }
__device__ __forceinline__ float fast_rcp (float x) { return __builtin_amdgcn_rcpf(x); }

// Bank-conflict swizzle: rotate low 5 bits of the slot right by 1 (bijective
// within every 32-slot chunk; 3072 = 96*32). 16B slots: bank-quad group =
// (s>>1)&7; stride-6 slot progressions -> group stride 3 (odd) ->
// conflict-free b128 gathers AND own-slot writes (validated R8/R9:
// conflicts 1.62e7 -> 9.2e5).
__device__ __forceinline__ int swz(int s) {
    return (s & ~31) | ((s >> 1) & 15) | ((s & 1) << 4);
}

__global__ __launch_bounds__(T, 4)   // min 4 waves/EU -> VGPR cap 256/4 = 64
void bp_decode(const float* __restrict__ llr,
               const float* __restrict__ w_iter,
               const float* __restrict__ llr_iter,
               const float* __restrict__ w_final,
               const float* __restrict__ llr_final,
               const int*  __restrict__ v_sum_idx,
               const int*  __restrict__ edge_var,
               const int*  __restrict__ final_idx,
               float* __restrict__ out)
{
    __shared__ v4f Ad[EEDG];   // 49152 B; 2 blocks/CU co-resident

    const int  tid = threadIdx.x;
    const long b0  = (long)blockIdx.x * ROWS;

    // ---- static per-thread graph data (my check = tid, edges 6*tid..6*tid+5) ----
    unsigned nbp[6];    // my 12 neighbor LDS slots (swizzled), 2x16b packed
    unsigned varp[3];   // my 6 variable ids, 2x16b packed
    v4f      Lpre[6];   // llr (4 rows) * LOG2E per edge
    {
        const int4* p = (const int4*)(v_sum_idx + 12 * tid);  // 48B-aligned
        int4 q0 = p[0], q1 = p[1], q2 = p[2];
        nbp[0] = (unsigned)swz(q0.x) | ((unsigned)swz(q0.y) << 16);
        nbp[1] = (unsigned)swz(q0.z) | ((unsigned)swz(q0.w) << 16);
        nbp[2] = (unsigned)swz(q1.x) | ((unsigned)swz(q1.y) << 16);
        nbp[3] = (unsigned)swz(q1.z) | ((unsigned)swz(q1.w) << 16);
        nbp[4] = (unsigned)swz(q2.x) | ((unsigned)swz(q2.y) << 16);
        nbp[5] = (unsigned)swz(q2.z) | ((unsigned)swz(q2.w) << 16);
    }
    {
        int var[6];
        const int2* p = (const int2*)(edge_var + 6 * tid);    // 24B-aligned
        int2 q0 = p[0], q1 = p[1], q2 = p[2];
        var[0]=q0.x; var[1]=q0.y; var[2]=q1.x; var[3]=q1.y; var[4]=q2.x; var[5]=q2.y;
        #pragma unroll
        for (int i = 0; i < 3; ++i)
            varp[i] = (unsigned)var[2*i] | ((unsigned)var[2*i+1] << 16);
        #pragma unroll
        for (int j = 0; j < 6; ++j) {
            v4f L;
            L.x = llr[(b0 + 0) * NVAR + var[j]];
            L.y = llr[(b0 + 1) * NVAR + var[j]];
            L.z = llr[(b0 + 2) * NVAR + var[j]];
            L.w = llr[(b0 + 3) * NVAR + var[j]];
            Lpre[j] = L * LOG2E;
        }
    }

    const int own = 6 * tid;

    // prefetch iteration 0 uniforms
    float w[12], lv[6];
    {
        const float* p = w_iter + 12 * tid;
        float4 a = ((const float4*)p)[0], b = ((const float4*)p)[1], c = ((const float4*)p)[2];
        w[0]=a.x; w[1]=a.y; w[2]=a.z;  w[3]=a.w;
        w[4]=b.x; w[5]=b.y; w[6]=b.z;  w[7]=b.w;
        w[8]=c.x; w[9]=c.y; w[10]=c.z; w[11]=c.w;
        #pragma unroll
        for (int i = 0; i < 3; ++i) {
            unsigned q = varp[i];
            lv[2*i]   = llr_iter[q & 0xffffu];
            lv[2*i+1] = llr_iter[q >> 16];
        }
    }

    __syncthreads();

    #pragma unroll 2
    for (int it = 0; it < NITER; ++it) {
        // accumulators seeded with channel term; LDS gathers folded in
        // immediately (peak live small -> no spills)
        v4f a[6];
        #pragma unroll
        for (int j = 0; j < 6; ++j) a[j] = Lpre[j] * lv[j];
        if (it) {   // iter 0: messages are all zero -> gathers elided exactly
            #pragma unroll
            for (int i = 0; i < 6; ++i) {
                unsigned p  = nbp[i];
                v4f ga = Ad[p & 0xffffu];     // ds_read_b128, conflict-free
                v4f gb = Ad[p >> 16];
                a[i] = a[i] + w[2*i] * ga + w[2*i+1] * gb;   // pk fma
            }
        }

        __syncthreads();   // all gathers landed before anyone overwrites in place

        // prefetch next iteration's uniforms; latency hides under transc phase
        {
            const int itn = (it + 1 < NITER) ? it + 1 : it;   // clamp, no OOB
            const float* p = w_iter + itn * (EEDG * 2) + 12 * tid;
            float4 qa = ((const float4*)p)[0], qb = ((const float4*)p)[1], qc = ((const float4*)p)[2];
            const float* lit = llr_iter + itn * NVAR;
            float lvn[6];
            #pragma unroll
            for (int i = 0; i < 3; ++i) {
                unsigned q = varp[i];
                lvn[2*i]   = lit[q & 0xffffu];
                lvn[2*i+1] = lit[q >> 16];
            }

            // z-domain check update (uses current w, lv via a[])
            v4f zm[6], zp[6];
            #pragma unroll
            for (int j = 0; j < 6; ++j) {
                v4f aa = __builtin_elementwise_min(a[j], (v4f)(ACLMP));
                v4f z;
                z.x = fast_exp2(aa.x);
                z.y = fast_exp2(aa.y);
                z.z = fast_exp2(aa.z);
                z.w = fast_exp2(aa.w);
                zm[j] = z - 1.f;
                zp[j] = z + 1.f;
            }
            v4f A[6], B[6];
            {
                v4f P1=zm[0], P2=P1*zm[1], P3=P2*zm[2], P4=P3*zm[3], P5=P4*zm[4];
                v4f S4=zm[5], S3=S4*zm[4], S2=S3*zm[3], S1=S2*zm[2], S0=S1*zm[1];
                A[0]=S0; A[1]=P1*S1; A[2]=P2*S2; A[3]=P3*S3; A[4]=P4*S4; A[5]=P5;
            }
            {
                v4f P1=zp[0], P2=P1*zp[1], P3=P2*zp[2], P4=P3*zp[3], P5=P4*zp[4];
                v4f S4=zp[5], S3=S4*zp[4], S2=S3*zp[3], S1=S2*zp[2], S0=S1*zp[1];
                B[0]=S0; B[1]=P1*S1; B[2]=P2*S2; B[3]=P3*S3; B[4]=P4*S4; B[5]=P5;
            }
            #pragma unroll
            for (int j = 0; j < 6; ++j) {
                v4f num = KAPPA * A[j] + B[j];    // pk fma
                v4f den = B[j] - KAPPA * A[j];    // pk fma
                v4f d;
                d.x = fast_log2(num.x) - fast_log2(den.x);
                d.y = fast_log2(num.y) - fast_log2(den.y);
                d.z = fast_log2(num.z) - fast_log2(den.z);
                d.w = fast_log2(num.w) - fast_log2(den.w);
                Ad[swz(own + j)] = d;             // ds_write_b128, conflict-free
            }

            // rotate prefetched uniforms into place (unroll-2 elides the movs)
            w[0]=qa.x; w[1]=qa.y; w[2]=qa.z;  w[3]=qa.w;
            w[4]=qb.x; w[5]=qb.y; w[6]=qb.z;  w[7]=qb.w;
            w[8]=qc.x; w[9]=qc.y; w[10]=qc.z; w[11]=qc.w;
            #pragma unroll
            for (int j = 0; j < 6; ++j) lv[j] = lvn[j];
        }

        __syncthreads();   // writes visible before next iteration's gathers
    }

    // ---- final marginalization: variable tid (the 512 output vars), 4 rows ----
    {
        int f0 = swz(final_idx[3*tid]), f1 = swz(final_idx[3*tid + 1]), f2 = swz(final_idx[3*tid + 2]);
        v4f d0 = Ad[f0];
        v4f d1 = Ad[f1];
        v4f d2 = Ad[f2];
        float wf0 = w_final[3*tid], wf1 = w_final[3*tid + 1], wf2 = w_final[3*tid + 2];
        float lf  = llr_final[tid];
        v4f l;
        l.x = llr[(b0 + 0) * NVAR + tid];
        l.y = llr[(b0 + 1) * NVAR + tid];
        l.z = llr[(b0 + 2) * NVAR + tid];
        l.w = llr[(b0 + 3) * NVAR + tid];

        v4f fin = (d0 * wf0 + d1 * wf1 + d2 * wf2) * LN2;   // c2v = ln2 * d
        v4f v   = l * lf + fin;
        out[(b0 + 0) * NOUT + tid] = fast_rcp(1.f + fast_exp2(-v.x * LOG2E));
        out[(b0 + 1) * NOUT + tid] = fast_rcp(1.f + fast_exp2(-v.y * LOG2E));
        out[(b0 + 2) * NOUT + tid] = fast_rcp(1.f + fast_exp2(-v.z * LOG2E));
        out[(b0 + 3) * NOUT + tid] = fast_rcp(1.f + fast_exp2(-v.w * LOG2E));
    }
}

} // namespace

extern "C" void kernel_launch(void* const* d_in, const int* in_sizes, int n_in,
                              void* d_out, int out_size, void* d_ws, size_t ws_size,
                              hipStream_t stream)
{
    const float* llr       = (const float*)d_in[0];
    const float* w_iter    = (const float*)d_in[1];
    const float* llr_iter  = (const float*)d_in[2];
    const float* w_final   = (const float*)d_in[3];
    const float* llr_final = (const float*)d_in[4];
    const int*   v_sum_idx = (const int*)d_in[5];
    // d_in[6] = c_prod_idx: unused (check groups are consecutive by construction)
    const int*   edge_var  = (const int*)d_in[7];
    const int*   final_idx = (const int*)d_in[8];
    float* outp = (float*)d_out;

    dim3 grid(BATCH / ROWS), block(T);
    hipLaunchKernelGGL(bp_decode, grid, block, 0, stream,
                       llr, w_iter, llr_iter, w_final, llr_final,
                       v_sum_idx, edge_var, final_idx, outp);
}

// Round 9
// 209.031 us; speedup vs baseline: 1.8026x; 1.0827x over previous
//
#include <hip/hip_runtime.h>

// Weighted BP decoder, (3,6)-regular Tanner graph.
// Check r owns edges 6r..6r+5 (row-major nonzeros of H) -> check-side extrinsic
// products are in-register prefix/suffix products (c_prod_idx unused).
//
// Messages in log2 domain: d = c2v/ln2. With z = exp2(a), t = tanh(a*ln2/2)
// = (z-1)/(z+1); extrinsic product p = A/B with A = prod(z-1), B = prod(z+1)
// (all-but-one). Then
//   d_new = log2(B + kappa*A) - log2(B - kappa*A)
// -> per edge-row transcendentals: exp2 + 2*log2 (tanh/atanh never formed).
// Exponent clamped at 24 (== z <= 2^24): 5-way products <= 2^120, and
// B >= |A| keeps both log args >= (1-kappa)*B > 0.
//
// R14 = R9 restored (R13 had a typo: missing ')' in swz). The verified
// session optimum: 146 us dispatch / 206.6 us bench (round 4).
//
// Final session map (all measured):
//  - Bank-conflict swizzle: KEPT (+6 us; SQ_LDS_BANK_CONFLICT 1.62e7->9.2e5).
//  - Occupancy: LDS co-residency pool ~96 KB -> 2 blocks/CU at 48 KB; VGPR
//    file = 256/lane/SIMD, __launch_bounds__(T,n) caps at 256/n; 4 waves/SIMD
//    @ 64 VGPR * ROWS=4 = 16 rows in flight is the optimum. More waves needs
//    <=42 VGPR (unreachable); ROWS=2 halves per-wave work at unchanged
//    occupancy (+24 us overhead, R7).
//  - Barrier halving via double-buffer (R8): LOSES -- 1 block/8 waves can't
//    cover latency; TLP cover beats barrier elimination (177 us).
//  - Persistence / iter-0 elision (R10/R11/R12): R9's allocation is EXACTLY
//    saturated at the 64-VGPR cap; every perturbation (group loop, tail
//    peel, setprio fences, even a 2-SALU uniform branch) tips it into
//    scratch spill (FETCH 18.8 -> 26..884 MB, 166..330 us). The ~3 us of
//    dead iter-0 work is unreachable.
//  - Residual vs ~63 us serial-issue floor: barrier-convoy + trans-chain
//    stalls; both structural escapes are measured losses. Converged.

namespace {

typedef float v4f __attribute__((ext_vector_type(4)));

constexpr int T      = 512;   // threads/block == checks
constexpr int ROWS   = 4;     // batch rows per block (v4f-packed)
constexpr int EEDG   = 3072;
constexpr int NVAR   = 1024;
constexpr int NITER  = 10;
constexpr int BATCH  = 8192;
constexpr int NOUT   = 512;   // N - M outputs per row

constexpr float LOG2E = 1.4426950408889634f;
constexpr float LN2   = 0.6931471805599453f;
constexpr float KAPPA = 0.999995f;
constexpr float ACLMP = 24.0f;   // exp2 arg clamp == z <= 2^24

__device__ __forceinline__ float fast_exp2(float x) { return __builtin_amdgcn_exp2f(x); }
__device__ __forceinline__ float fast_log2(float x) { return __builtin_amdgcn_logf(x); }
__device__ __forceinline__ float fast_rcp (float x) { return __builtin_amdgcn_rcpf(x); }

// Bank-conflict swizzle: rotate low 5 bits of the slot right by 1 (bijective
// within every 32-slot chunk; 3072 = 96*32, swizzled slots stay in [0,3072)).
// 16B slots: bank-quad group = (s>>1)&7; stride-6 slot progressions ->
// group stride 3 (odd) -> conflict-free b128 gathers AND own-slot writes.
__device__ __forceinline__ int swz(int s) {
    return (s & ~31) | ((s >> 1) & 15) | ((s & 1) << 4);
}

__global__ __launch_bounds__(T, 4)   // min 4 waves/EU -> VGPR cap 256/4 = 64
void bp_decode(const float* __restrict__ llr,
               const float* __restrict__ w_iter,
               const float* __restrict__ llr_iter,
               const float* __restrict__ w_final,
               const float* __restrict__ llr_final,
               const int*  __restrict__ v_sum_idx,
               const int*  __restrict__ edge_var,
               const int*  __restrict__ final_idx,
               float* __restrict__ out)
{
    __shared__ v4f Ad[EEDG];   // 49152 B; 2 blocks/CU co-resident

    const int  tid = threadIdx.x;
    const long b0  = (long)blockIdx.x * ROWS;

    // ---- init: d = 0 (swizzle is a bijection -> full cover) ----
    #pragma unroll
    for (int k = 0; k < 6; ++k)
        Ad[k * T + tid] = (v4f)(0.f);

    // ---- static per-thread graph data (my check = tid, edges 6*tid..6*tid+5) ----
    unsigned nbp[6];    // my 12 neighbor LDS slots (swizzled), 2x16b packed
    unsigned varp[3];   // my 6 variable ids, 2x16b packed
    v4f      Lpre[6];   // llr (4 rows) * LOG2E per edge
    {
        const int4* p = (const int4*)(v_sum_idx + 12 * tid);  // 48B-aligned
        int4 q0 = p[0], q1 = p[1], q2 = p[2];
        nbp[0] = (unsigned)swz(q0.x) | ((unsigned)swz(q0.y) << 16);
        nbp[1] = (unsigned)swz(q0.z) | ((unsigned)swz(q0.w) << 16);
        nbp[2] = (unsigned)swz(q1.x) | ((unsigned)swz(q1.y) << 16);
        nbp[3] = (unsigned)swz(q1.z) | ((unsigned)swz(q1.w) << 16);
        nbp[4] = (unsigned)swz(q2.x) | ((unsigned)swz(q2.y) << 16);
        nbp[5] = (unsigned)swz(q2.z) | ((unsigned)swz(q2.w) << 16);
    }
    {
        int var[6];
        const int2* p = (const int2*)(edge_var + 6 * tid);    // 24B-aligned
        int2 q0 = p[0], q1 = p[1], q2 = p[2];
        var[0]=q0.x; var[1]=q0.y; var[2]=q1.x; var[3]=q1.y; var[4]=q2.x; var[5]=q2.y;
        #pragma unroll
        for (int i = 0; i < 3; ++i)
            varp[i] = (unsigned)var[2*i] | ((unsigned)var[2*i+1] << 16);
        #pragma unroll
        for (int j = 0; j < 6; ++j) {
            v4f L;
            L.x = llr[(b0 + 0) * NVAR + var[j]];
            L.y = llr[(b0 + 1) * NVAR + var[j]];
            L.z = llr[(b0 + 2) * NVAR + var[j]];
            L.w = llr[(b0 + 3) * NVAR + var[j]];
            Lpre[j] = L * LOG2E;
        }
    }

    const int own = 6 * tid;

    // prefetch iteration 0 uniforms
    float w[12], lv[6];
    {
        const float* p = w_iter + 12 * tid;
        float4 a = ((const float4*)p)[0], b = ((const float4*)p)[1], c = ((const float4*)p)[2];
        w[0]=a.x; w[1]=a.y; w[2]=a.z;  w[3]=a.w;
        w[4]=b.x; w[5]=b.y; w[6]=b.z;  w[7]=b.w;
        w[8]=c.x; w[9]=c.y; w[10]=c.z; w[11]=c.w;
        #pragma unroll
        for (int i = 0; i < 3; ++i) {
            unsigned q = varp[i];
            lv[2*i]   = llr_iter[q & 0xffffu];
            lv[2*i+1] = llr_iter[q >> 16];
        }
    }

    __syncthreads();

    #pragma unroll 2
    for (int it = 0; it < NITER; ++it) {
        // accumulators seeded with channel term; LDS gathers folded in
        // immediately (peak live small -> no spills)
        v4f a[6];
        #pragma unroll
        for (int j = 0; j < 6; ++j) a[j] = Lpre[j] * lv[j];
        #pragma unroll
        for (int i = 0; i < 6; ++i) {
            unsigned p  = nbp[i];
            v4f ga = Ad[p & 0xffffu];     // ds_read_b128, conflict-free
            v4f gb = Ad[p >> 16];
            a[i] = a[i] + w[2*i] * ga + w[2*i+1] * gb;   // pk fma
        }

        __syncthreads();   // all gathers landed before anyone overwrites in place

        // prefetch next iteration's uniforms; latency hides under transc phase
        {
            const int itn = (it + 1 < NITER) ? it + 1 : it;   // clamp, no OOB
            const float* p = w_iter + itn * (EEDG * 2) + 12 * tid;
            float4 qa = ((const float4*)p)[0], qb = ((const float4*)p)[1], qc = ((const float4*)p)[2];
            const float* lit = llr_iter + itn * NVAR;
            float lvn[6];
            #pragma unroll
            for (int i = 0; i < 3; ++i) {
                unsigned q = varp[i];
                lvn[2*i]   = lit[q & 0xffffu];
                lvn[2*i+1] = lit[q >> 16];
            }

            // z-domain check update (uses current w, lv via a[])
            v4f zm[6], zp[6];
            #pragma unroll
            for (int j = 0; j < 6; ++j) {
                v4f aa = __builtin_elementwise_min(a[j], (v4f)(ACLMP));
                v4f z;
                z.x = fast_exp2(aa.x);
                z.y = fast_exp2(aa.y);
                z.z = fast_exp2(aa.z);
                z.w = fast_exp2(aa.w);
                zm[j] = z - 1.f;
                zp[j] = z + 1.f;
            }
            v4f A[6], B[6];
            {
                v4f P1=zm[0], P2=P1*zm[1], P3=P2*zm[2], P4=P3*zm[3], P5=P4*zm[4];
                v4f S4=zm[5], S3=S4*zm[4], S2=S3*zm[3], S1=S2*zm[2], S0=S1*zm[1];
                A[0]=S0; A[1]=P1*S1; A[2]=P2*S2; A[3]=P3*S3; A[4]=P4*S4; A[5]=P5;
            }
            {
                v4f P1=zp[0], P2=P1*zp[1], P3=P2*zp[2], P4=P3*zp[3], P5=P4*zp[4];
                v4f S4=zp[5], S3=S4*zp[4], S2=S3*zp[3], S1=S2*zp[2], S0=S1*zp[1];
                B[0]=S0; B[1]=P1*S1; B[2]=P2*S2; B[3]=P3*S3; B[4]=P4*S4; B[5]=P5;
            }
            #pragma unroll
            for (int j = 0; j < 6; ++j) {
                v4f num = KAPPA * A[j] + B[j];    // pk fma
                v4f den = B[j] - KAPPA * A[j];    // pk fma
                v4f d;
                d.x = fast_log2(num.x) - fast_log2(den.x);
                d.y = fast_log2(num.y) - fast_log2(den.y);
                d.z = fast_log2(num.z) - fast_log2(den.z);
                d.w = fast_log2(num.w) - fast_log2(den.w);
                Ad[swz(own + j)] = d;             // ds_write_b128, conflict-free
            }

            // rotate prefetched uniforms into place (unroll-2 elides the movs)
            w[0]=qa.x; w[1]=qa.y; w[2]=qa.z;  w[3]=qa.w;
            w[4]=qb.x; w[5]=qb.y; w[6]=qb.z;  w[7]=qb.w;
            w[8]=qc.x; w[9]=qc.y; w[10]=qc.z; w[11]=qc.w;
            #pragma unroll
            for (int j = 0; j < 6; ++j) lv[j] = lvn[j];
        }

        __syncthreads();   // writes visible before next iteration's gathers
    }

    // ---- final marginalization: variable tid (the 512 output vars), 4 rows ----
    {
        int f0 = swz(final_idx[3*tid]), f1 = swz(final_idx[3*tid + 1]), f2 = swz(final_idx[3*tid + 2]);
        v4f d0 = Ad[f0];
        v4f d1 = Ad[f1];
        v4f d2 = Ad[f2];
        float wf0 = w_final[3*tid], wf1 = w_final[3*tid + 1], wf2 = w_final[3*tid + 2];
        float lf  = llr_final[tid];
        v4f l;
        l.x = llr[(b0 + 0) * NVAR + tid];
        l.y = llr[(b0 + 1) * NVAR + tid];
        l.z = llr[(b0 + 2) * NVAR + tid];
        l.w = llr[(b0 + 3) * NVAR + tid];

        v4f fin = (d0 * wf0 + d1 * wf1 + d2 * wf2) * LN2;   // c2v = ln2 * d
        v4f v   = l * lf + fin;
        out[(b0 + 0) * NOUT + tid] = fast_rcp(1.f + fast_exp2(-v.x * LOG2E));
        out[(b0 + 1) * NOUT + tid] = fast_rcp(1.f + fast_exp2(-v.y * LOG2E));
        out[(b0 + 2) * NOUT + tid] = fast_rcp(1.f + fast_exp2(-v.z * LOG2E));
        out[(b0 + 3) * NOUT + tid] = fast_rcp(1.f + fast_exp2(-v.w * LOG2E));
    }
}

} // namespace

extern "C" void kernel_launch(void* const* d_in, const int* in_sizes, int n_in,
                              void* d_out, int out_size, void* d_ws, size_t ws_size,
                              hipStream_t stream)
{
    const float* llr       = (const float*)d_in[0];
    const float* w_iter    = (const float*)d_in[1];
    const float* llr_iter  = (const float*)d_in[2];
    const float* w_final   = (const float*)d_in[3];
    const float* llr_final = (const float*)d_in[4];
    const int*   v_sum_idx = (const int*)d_in[5];
    // d_in[6] = c_prod_idx: unused (check groups are consecutive by construction)
    const int*   edge_var  = (const int*)d_in[7];
    const int*   final_idx = (const int*)d_in[8];
    float* outp = (float*)d_out;

    dim3 grid(BATCH / ROWS), block(T);
    hipLaunchKernelGGL(bp_decode, grid, block, 0, stream,
                       llr, w_iter, llr_iter, w_final, llr_final,
                       v_sum_idx, edge_var, final_idx, outp);
}